// Round 7
// baseline (164.856 us; speedup 1.0000x reference)
//
#include <hip/hip_runtime.h>

// Cost volume: B=4, C=32, H=256, W=256, D=9, G=8, cpg=4
// out[b,g,d,h,w] = mean_{c in group g} var(warp_l, warp_r, feat_ref)
//
// R8: XCD-band task swizzle, single-variable change on top of R7.
// R1-R7 varied VALU intensity, latency structure, LDS use, pipelining,
// access width (4/8/16B), occupancy (9-70%) -- duration pinned at
// 54-56us, demand 177MB => ~3.3 TB/s service vs 6.3 TB/s copy ceiling.
// Last structural delta vs a copy: stream locality. Default round-robin
// block->XCD mapping shreds each XCD's DRAM traffic into ~1KB slivers
// from hundreds of planes. Swizzle so XCD j (= bid%8 per m09/m157) owns
// a CONTIGUOUS task band: task = (bid%8)*1024 + bid/8. Then each XCD's
// 32 CUs sweep consecutive rows of one (b,g): 13 read + 9 write streams,
// each linear in 32KB chunks -> dense DRAM bursts, amortized turnaround.
// Everything else is byte-identical to R7 (dwordx2 everywhere, 128-thr
// blocks, R3's verified LDS core + hat-weight/Q-S^2/3 math).

#define B_ 4
#define C_ 32
#define H_ 256
#define W_ 256
#define D_ 9
#define G_ 8
#define CPG 4
#define HW_ (H_ * W_)
#define SWPAD 264   // slots 0..259 used (x in [-2, W+1]); padded stride

typedef float v2f __attribute__((ext_vector_type(2)));

static __device__ __forceinline__ v2f sp(float x) { v2f r; r.x = x; r.y = x; return r; }

__global__ __launch_bounds__(128) void cost_volume_kernel(
    const float* __restrict__ fref,
    const float* __restrict__ fls,
    const float* __restrict__ frs,
    const float* __restrict__ disp0,
    float* __restrict__ out)
{
    const float kRes[D_] = {-0.4f, -0.3f, -0.2f, -0.1f, 0.0f,
                             0.1f,  0.2f,  0.3f,  0.4f};

    __shared__ float sL[CPG][SWPAD];
    __shared__ float sR[CPG][SWPAD];

    // ---- XCD-band swizzle: XCD j = bid%8 gets contiguous tasks ----
    // task = j*1024 + (bid>>3), bijective over 8192.
    // task -> (bg, h): h = task & 255, bg = task >> 8; b = bg>>3, g = bg&7.
    const int bid = blockIdx.x;
    const int task = (bid & 7) * (B_ * G_ * H_ / 8) + (bid >> 3);
    const int h  = task & (H_ - 1);
    const int bg = task >> 8;           // 0..31
    const int b  = bg >> 3;
    const int g  = bg & 7;
    const int t  = threadIdx.x;         // 0..127
    const int w0 = t << 1;              // pixels w0, w0+1

    // disp for both pixels (dwordx2)
    const v2f dsp = *(const v2f*)(disp0 + (unsigned)((b * H_ + h) * W_ + w0));

    const unsigned rowbase = (unsigned)(((b * C_ + g * CPG) * HW_) + h * W_);
    const float* __restrict__ refrow = fref + rowbase;
    const float* __restrict__ lsrow  = fls  + rowbase;
    const float* __restrict__ rsrow  = frs  + rowbase;

    // ---- stage L/R rows (halo'd) into LDS, all dwordx2 ----
    {
        const int x0 = w0 - 2;                        // even, -2..252
        const bool v = (x0 >= 0);                     // only thread 0 is OOB
        #pragma unroll
        for (int cc = 0; cc < CPG; ++cc) {
            v2f mv = v ? *(const v2f*)(lsrow + cc * HW_ + x0) : sp(0.0f);
            *(v2f*)&sL[cc][w0] = mv;                  // slots x0+2 = w0, w0+1
            v2f mr = v ? *(const v2f*)(rsrow + cc * HW_ + x0) : sp(0.0f);
            *(v2f*)&sR[cc][w0] = mr;
        }
        if (t < 16) {                                 // halo slots 256..259
            const int side = t >> 3;                  // 0=L 1=R
            const int cc   = (t >> 1) & 3;
            const int part = t & 1;                   // 0: x=254,255  1: x=256,257
            v2f hv = sp(0.0f);
            if (part == 0) {
                const float* src = (side ? rsrow : lsrow) + cc * HW_ + 254;
                hv = *(const v2f*)src;
            }
            float* dst = side ? &sR[cc][256 + 2 * part] : &sL[cc][256 + 2 * part];
            *(v2f*)dst = hv;
        }
    }

    // fref for both pixels, all 4 channels (dwordx2)
    v2f F[CPG];
    #pragma unroll
    for (int cc = 0; cc < CPG; ++cc)
        F[cc] = *(const v2f*)(refrow + cc * HW_ + w0);

    __syncthreads();

    const unsigned obase = (unsigned)(((b * G_ + g) * D_) * HW_ + h * W_ + w0);
    float vals0[D_];                                  // pixel-0 stash

    #pragma unroll
    for (int p = 0; p < 2; ++p) {
        const int w = w0 + p;
        const float wf = (float)w;
        const float dbase = p ? dsp.y : dsp.x;

        // ---- disp-dependent setup (R3 math, verified) ----
        const float s0 = wf + dbase;
        const int i0l = (int)floorf(s0 - 0.4f);
        int relL = i0l - w;
        relL = relL < -1 ? -1 : (relL > 0 ? 0 : relL);
        const float a1l = (s0 - (float)(w + relL)) - 1.0f;

        const float s1 = wf - dbase;
        const int i0r = (int)floorf(s1 - 0.4f);
        int relR = i0r - w;
        relR = relR < -2 ? -2 : (relR > -1 ? -1 : relR);
        const float a1r = (s1 - (float)(w + relR)) - 1.0f;

        const int baseL = w + relL + 2;
        const int baseR = w + relR + 2;

        v2f fr01, fr23;
        fr01.x = p ? F[0].y : F[0].x;  fr01.y = p ? F[1].y : F[1].x;
        fr23.x = p ? F[2].y : F[2].x;  fr23.y = p ? F[3].y : F[3].x;
        const float frq = fr01.x * fr01.x + fr01.y * fr01.y
                        + fr23.x * fr23.x + fr23.y * fr23.y;

        v2f tl01[3], tl23[3], tr01[3], tr23[3];
        #pragma unroll
        for (int k = 0; k < 3; ++k) {
            tl01[k].x = sL[0][baseL + k];
            tl01[k].y = sL[1][baseL + k];
            tl23[k].x = sL[2][baseL + k];
            tl23[k].y = sL[3][baseL + k];
            tr01[k].x = sR[0][baseR + k];
            tr01[k].y = sR[1][baseR + k];
            tr23[k].x = sR[2][baseR + k];
            tr23[k].y = sR[3][baseR + k];
        }

        #pragma unroll
        for (int d = 0; d < D_; ++d) {
            const float tlw = a1l + kRes[d];
            const float W0l = fmaxf(-tlw, 0.0f);
            const float W1l = 1.0f - fabsf(tlw);
            const float W2l = fmaxf(tlw, 0.0f);
            const float trw = a1r - kRes[d];
            const float W0r = fmaxf(-trw, 0.0f);
            const float W1r = 1.0f - fabsf(trw);
            const float W2r = fmaxf(trw, 0.0f);

            v2f wl01 = tl01[0] * sp(W0l) + tl01[1] * sp(W1l) + tl01[2] * sp(W2l);
            v2f wl23 = tl23[0] * sp(W0l) + tl23[1] * sp(W1l) + tl23[2] * sp(W2l);
            v2f wr01 = tr01[0] * sp(W0r) + tr01[1] * sp(W1r) + tr01[2] * sp(W2r);
            v2f wr23 = tr23[0] * sp(W0r) + tr23[1] * sp(W1r) + tr23[2] * sp(W2r);

            v2f q   = wl01 * wl01 + wr01 * wr01 + wl23 * wl23 + wr23 * wr23;
            v2f s01 = wl01 + wr01 + fr01;
            v2f s23 = wl23 + wr23 + fr23;
            v2f s2  = s01 * s01 + s23 * s23;

            const float Q  = q.x + q.y + frq;
            const float S2 = s2.x + s2.y;
            const float val = (Q - S2 * (1.0f / 3.0f)) * (1.0f / 12.0f);

            if (p == 0) {
                vals0[d] = val;
            } else {
                v2f o; o.x = vals0[d]; o.y = val;     // dwordx2 store
                __builtin_nontemporal_store(
                    o, (v2f*)(out + obase + (unsigned)d * (unsigned)HW_));
            }
        }
    }
}

extern "C" void kernel_launch(void* const* d_in, const int* in_sizes, int n_in,
                              void* d_out, int out_size, void* d_ws, size_t ws_size,
                              hipStream_t stream) {
    const float* fref  = (const float*)d_in[0];
    const float* fls   = (const float*)d_in[1];
    const float* frs   = (const float*)d_in[2];
    const float* disp0 = (const float*)d_in[3];
    float* out = (float*)d_out;

    dim3 grid(B_ * G_ * H_);    // 8192 blocks; XCD-banded task order
    dim3 block(128);
    cost_volume_kernel<<<grid, block, 0, stream>>>(fref, fls, frs, disp0, out);
}